// Round 6
// baseline (471.862 us; speedup 1.0000x reference)
//
#include <hip/hip_runtime.h>
#include <hip/hip_bf16.h>
#include <stdint.h>

// QuantizedLinear: y = x @ (Wq * scale[:,None])^T + bias
// Round 6: i8 MFMA, 128x128, BK=128, 2 blocks/CU. Round-5's reg-dbuf idea on
// round-4's EXPLICIT waitcnt skeleton (round-5 failed: relying on __syncthreads
// implicit drains leaves (a) newer same-buffer ds_reads unresolved at restage
// [compiler MFMA auto-wait only covers operands], (b) no vmcnt ordering for
// gload_lds->ds_read RAW [compiler doesn't alias-model gload_lds's LDS write]).
// Schedule per tile t (p=t&1, bp=buf[p], bq=buf[p^1]):
//   P0: RD afY<-bp.A(K1) | STAGE A(t+1)->bq.A | MFMA(afX,bf0)   [ops >=1 phase old]
//       lgkmcnt(0)  [ALL reads of bp.B resolved]  barrier A
//   P1: STAGE B(t+2)->bp.B [safe: barA postdates block-wide B-read drain]
//       MFMA(afY,bf1) | vmcnt(4) [A(t+1),B(t+1) landed; B(t+2) in flight]
//       barrier B | RD afX,bf0,bf1 <- bq (tile t+1)  [complete under next MFMA]

#define M_TOTAL 8192
#define K_TOTAL 4096
#define N_TOTAL 11008
#define NT 32
#define NBM 64
#define NBN 86

typedef __attribute__((ext_vector_type(4))) int int4v;

// ---------------- x quantization: per-row absmax -> int8 (round-4 verbatim) ----------------

__global__ __launch_bounds__(256) void quant_x_kernel(const float* __restrict__ x,
                                                      signed char* __restrict__ xq,
                                                      float* __restrict__ sx) {
    const int row = blockIdx.x;
    const int tid = threadIdx.x;
    const float* xr = x + (size_t)row * K_TOTAL + tid * 16;

    float4 v0 = reinterpret_cast<const float4*>(xr)[0];
    float4 v1 = reinterpret_cast<const float4*>(xr)[1];
    float4 v2 = reinterpret_cast<const float4*>(xr)[2];
    float4 v3 = reinterpret_cast<const float4*>(xr)[3];

    float m = 0.f;
    m = fmaxf(m, fmaxf(fmaxf(fabsf(v0.x), fabsf(v0.y)), fmaxf(fabsf(v0.z), fabsf(v0.w))));
    m = fmaxf(m, fmaxf(fmaxf(fabsf(v1.x), fabsf(v1.y)), fmaxf(fabsf(v1.z), fabsf(v1.w))));
    m = fmaxf(m, fmaxf(fmaxf(fabsf(v2.x), fabsf(v2.y)), fmaxf(fabsf(v2.z), fabsf(v2.w))));
    m = fmaxf(m, fmaxf(fmaxf(fabsf(v3.x), fabsf(v3.y)), fmaxf(fabsf(v3.z), fabsf(v3.w))));

    for (int d = 1; d < 64; d <<= 1) m = fmaxf(m, __shfl_xor(m, d));
    __shared__ float wm_[4];
    if ((tid & 63) == 0) wm_[tid >> 6] = m;
    __syncthreads();
    m = fmaxf(fmaxf(wm_[0], wm_[1]), fmaxf(wm_[2], wm_[3]));

    const float inv = (m > 0.f) ? (127.f / m) : 0.f;
    if (tid == 0) sx[row] = (m > 0.f) ? (m / 127.f) : 0.f;

    float tmp[16] = {v0.x,v0.y,v0.z,v0.w, v1.x,v1.y,v1.z,v1.w,
                     v2.x,v2.y,v2.z,v2.w, v3.x,v3.y,v3.z,v3.w};
    int q[16];
#pragma unroll
    for (int i = 0; i < 16; ++i) {
        int t = __float2int_rn(tmp[i] * inv);
        q[i] = t > 127 ? 127 : (t < -127 ? -127 : t);
    }
    int4v o;
#pragma unroll
    for (int w = 0; w < 4; ++w)
        o[w] = (q[w*4] & 255) | ((q[w*4+1] & 255) << 8) |
               ((q[w*4+2] & 255) << 16) | ((q[w*4+3] & 255) << 24);
    *reinterpret_cast<int4v*>(xq + (size_t)row * K_TOTAL + tid * 16) = o;
}

// ---------------- W unpack (round-4 verbatim) ----------------

__global__ __launch_bounds__(256) void cvt_w_kernel(const int* __restrict__ in,
                                                    signed char* __restrict__ out, int nitems) {
    bool is8 = false;
    for (int i = 0; i < 256; ++i) {
        int v = in[i];
        if (v < -127 || v > 127) { is8 = true; break; }
    }
    int stride = gridDim.x * blockDim.x;
    if (!is8) {
        for (int i = blockIdx.x * blockDim.x + threadIdx.x; i < nitems; i += stride) {
            const int* p = in + (size_t)i * 16;
            int4v o;
#pragma unroll
            for (int w = 0; w < 4; ++w)
                o[w] = (p[w*4] & 255) | ((p[w*4+1] & 255) << 8) |
                       ((p[w*4+2] & 255) << 16) | ((p[w*4+3] & 255) << 24);
            *reinterpret_cast<int4v*>(out + (size_t)i * 16) = o;
        }
    } else {
        const int4v* in16 = reinterpret_cast<const int4v*>(in);
        for (int i = blockIdx.x * blockDim.x + threadIdx.x; i < nitems; i += stride)
            *reinterpret_cast<int4v*>(out + (size_t)i * 16) = in16[i];
    }
}

// ---------------- 128x128 i8 GEMM, frag-ahead pipeline, 2 blocks/CU ----------------

#define GLOAD16(g, l) __builtin_amdgcn_global_load_lds( \
    (const __attribute__((address_space(1))) void*)(g), \
    (__attribute__((address_space(3))) void*)(l), 16, 0, 0)

// LDS (bytes): buf p*32768 + {A: [0,16K) | B: [16K,32K)}; tile t in buf[t&1].
// chunk = 8 rows = 1 KiB; wave wv stages chunks wv*4..wv*4+3 per operand.
// Swizzle: 16B granule g stored at g ^ (row&7); inverse applied on global src.

#define RD_A(dst, base, KX)                                                     \
    _Pragma("unroll")                                                           \
    for (int i_ = 0; i_ < 4; ++i_)                                              \
        dst[i_] = *(const int4v*)((base) + (wm * 64 + i_ * 16 + fr) * 128 + (KX));
#define RD_B(dst, base, KX)                                                     \
    _Pragma("unroll")                                                           \
    for (int n_ = 0; n_ < 4; ++n_)                                              \
        dst[n_] = *(const int4v*)((base) + 16384 + (wn * 64 + n_ * 16 + fr) * 128 + (KX));
#define MFMA16(fa, fb)                                                          \
    __builtin_amdgcn_s_setprio(1);                                              \
    _Pragma("unroll")                                                           \
    for (int i_ = 0; i_ < 4; ++i_) {                                            \
        _Pragma("unroll")                                                       \
        for (int n_ = 0; n_ < 4; ++n_)                                          \
            acc[i_][n_] = __builtin_amdgcn_mfma_i32_16x16x64_i8(                \
                fa[i_], fb[n_], acc[i_][n_], 0, 0, 0);                          \
    }                                                                           \
    __builtin_amdgcn_s_setprio(0);
#define STAGE_A(asrc, buf)                                                      \
    _Pragma("unroll")                                                           \
    for (int i_ = 0; i_ < 4; ++i_)                                              \
        GLOAD16((asrc) + soff[i_], (buf) + (c0 + i_) * 1024);
#define STAGE_B(bsrc, buf)                                                      \
    _Pragma("unroll")                                                           \
    for (int i_ = 0; i_ < 4; ++i_)                                              \
        GLOAD16((bsrc) + soff[i_], (buf) + 16384 + (c0 + i_) * 1024);

__global__ __launch_bounds__(256, 2) void gemm_kernel(const unsigned char* __restrict__ A,
                                                      const unsigned char* __restrict__ B,
                                                      const float* __restrict__ sx,
                                                      const float* __restrict__ scale,
                                                      const float* __restrict__ bias,
                                                      float* __restrict__ C) {
    __shared__ unsigned char sh[65536];  // 64 KiB -> 2 blocks/CU

    const int tid  = threadIdx.x;
    const int wv   = tid >> 6;
    const int lane = tid & 63;
    const int wm   = wv >> 1;
    const int wn   = wv & 1;

    // supertiled XCD swizzle: 5504 = 8 xcd * 688 (2 bands x 4bm, 4x4 supertiles, tail 4x2)
    const int xcd = blockIdx.x & 7;
    const int l   = blockIdx.x >> 3;
    const int band = l / 344;
    const int lb   = l - band * 344;
    const int st   = lb >> 4;
    const int r    = lb & 15;
    int bm_l, bn;
    if (st < 21) { bm_l = band * 4 + (r >> 2); bn = st * 4 + (r & 3); }
    else         { bm_l = band * 4 + (r >> 1); bn = 84 + (r & 1); }
    const int bm = xcd * 8 + bm_l;

    // fragment-read geometry (byte offsets)
    const int fr  = lane & 15;
    const int fq  = lane >> 4;
    const int swz = fr & 7;
    const int kx0 = (fq ^ swz) * 16;
    const int kx1 = ((4 + fq) ^ swz) * 16;

    // staging source offsets (inverse-swizzled granule)
    const int c0 = wv * 4;
    const int rl = lane >> 3;
    const int sg = (lane & 7) ^ rl;
    size_t soff[4];
#pragma unroll
    for (int i = 0; i < 4; ++i)
        soff[i] = (size_t)((c0 + i) * 8 + rl) * K_TOTAL + sg * 16;

    const unsigned char* aS = A + (size_t)bm * 128 * K_TOTAL;
    const unsigned char* bS = B + (size_t)bn * 128 * K_TOTAL;
    unsigned char* buf0 = sh;
    unsigned char* buf1 = sh + 32768;

    int4v acc[4][4] = {};
    int4v afX[4], afY[4], bf0v[4], bf1v[4];

    // ---- prologue: A(0),B(0)->buf0; B(1)->buf1.B; then frag reads of tile 0 ----
    STAGE_A(aS, buf0)
    STAGE_B(bS, buf0)
    STAGE_B(bS + 128, buf1)
    asm volatile("s_waitcnt vmcnt(4)" ::: "memory");   // tile0 landed; B(1) in flight
    __builtin_amdgcn_s_barrier();
    RD_A(afX, buf0, kx0)
    RD_B(bf0v, buf0, kx0)
    RD_B(bf1v, buf0, kx1)

    // ---- main loop ----
#pragma unroll 1
    for (int t = 0; t < NT; ++t) {
        const int p = t & 1;
        unsigned char* bp = p ? buf1 : buf0;
        unsigned char* bq = p ? buf0 : buf1;

        // P0: afY reads overlap MFMA; A(t+1) stage issue overlaps MFMA.
        // WAR(bq.A): last reads of bq.A resolved before t-1's barB (block-wide). OK.
        RD_A(afY, bp, kx1)
        if (t + 1 < NT) { STAGE_A(aS + (size_t)(t + 1) * 128, bq) }
        MFMA16(afX, bf0v)                                   // auto lgkm wait: operands only
        asm volatile("s_waitcnt lgkmcnt(0)" ::: "memory");  // ALL bp.B reads resolved (incl bf1v)
        __builtin_amdgcn_s_barrier();                       // barrier A

        // P1: B(t+2) into bp.B -- safe: barA postdates every wave's lgkmcnt(0).
        if (t + 2 < NT) { STAGE_B(bS + (size_t)(t + 2) * 128, bp) }
        MFMA16(afY, bf1v)
        if (t + 1 < NT) {
            if (t + 2 < NT) { asm volatile("s_waitcnt vmcnt(4)" ::: "memory"); }  // leave B(t+2)
            else            { asm volatile("s_waitcnt vmcnt(0)" ::: "memory"); }
        }
        __builtin_amdgcn_s_barrier();                       // barrier B: bq fully staged
        if (t + 1 < NT) {
            RD_A(afX, bq, kx0)                              // tile t+1 frags; complete
            RD_B(bf0v, bq, kx0)                             // under next P0's MFMA
            RD_B(bf1v, bq, kx1)
        }
    }

    // ---- epilogue: y = acc * sx[row]*scale[col] + bias[col] ----
    const int crow0 = bm * 128 + wm * 64;
    const int ccol0 = bn * 128 + wn * 64;
    float scv[4], bsv[4];
#pragma unroll
    for (int n = 0; n < 4; ++n) {
        const int col = ccol0 + n * 16 + fr;
        scv[n] = scale[col];
        bsv[n] = bias[col];
    }
#pragma unroll
    for (int fm = 0; fm < 4; ++fm) {
#pragma unroll
        for (int j = 0; j < 4; ++j) {
            const int row = crow0 + fm * 16 + fq * 4 + j;
            const float sr = sx[row];
            float* cp = C + (size_t)row * N_TOTAL + ccol0 + fr;
#pragma unroll
            for (int n = 0; n < 4; ++n)
                cp[n * 16] = (float)acc[fm][n][j] * (sr * scv[n]) + bsv[n];
        }
    }
}

// ---------------- fallback (ws too small): tiled f32 vector GEMM ----------------

__global__ __launch_bounds__(256) void gemm_fallback(const float* __restrict__ x,
                                                     const int* __restrict__ w,
                                                     const float* __restrict__ scale,
                                                     const float* __restrict__ bias,
                                                     float* __restrict__ C) {
    bool is8 = false;
    for (int i = 0; i < 256; ++i) {
        int v = w[i];
        if (v < -127 || v > 127) { is8 = true; break; }
    }
    const signed char* w8 = (const signed char*)w;

    __shared__ float As[64][16];
    __shared__ float Bs[64][16];
    const int nbn = N_TOTAL / 64;
    const int bm = blockIdx.x / nbn;
    const int bn = blockIdx.x % nbn;
    const int tid = threadIdx.x;
    const int tx = tid & 15, ty = tid >> 4;

    float acc[4][4] = {};
    for (int kt = 0; kt < K_TOTAL; kt += 16) {
        for (int i = 0; i < 4; ++i) {
            int idx = tid + i * 256;
            int rr = idx >> 4, cc = idx & 15;
            As[rr][cc] = x[(size_t)(bm * 64 + rr) * K_TOTAL + kt + cc];
            size_t widx = (size_t)(bn * 64 + rr) * K_TOTAL + kt + cc;
            Bs[rr][cc] = is8 ? (float)w8[widx] : (float)w[widx];
        }
        __syncthreads();
        for (int kk = 0; kk < 16; ++kk) {
            float a[4], b[4];
            for (int i = 0; i < 4; ++i) a[i] = As[ty * 4 + i][kk];
            for (int j = 0; j < 4; ++j) b[j] = Bs[tx * 4 + j][kk];
            for (int i = 0; i < 4; ++i)
                for (int j = 0; j < 4; ++j) acc[i][j] += a[i] * b[j];
        }
        __syncthreads();
    }
    for (int j = 0; j < 4; ++j) {
        int col = bn * 64 + tx * 4 + j;
        float s = scale[col], bb = bias[col];
        for (int i = 0; i < 4; ++i) {
            int row = bm * 64 + ty * 4 + i;
            C[(size_t)row * N_TOTAL + col] = acc[i][j] * s + bb;
        }
    }
}

// ---------------- launch ----------------

extern "C" void kernel_launch(void* const* d_in, const int* in_sizes, int n_in,
                              void* d_out, int out_size, void* d_ws, size_t ws_size,
                              hipStream_t stream) {
    const float* x     = (const float*)d_in[0];
    const int*   wq    = (const int*)d_in[1];
    const float* scale = (const float*)d_in[2];
    const float* bias  = (const float*)d_in[3];
    float*       out   = (float*)d_out;

    const size_t x_bytes = (size_t)M_TOTAL * K_TOTAL;
    const size_t w_bytes = (size_t)N_TOTAL * K_TOTAL;
    const size_t need = x_bytes + w_bytes + M_TOTAL * sizeof(float);

    if (ws_size >= need) {
        signed char* xq = (signed char*)d_ws;
        signed char* wb = (signed char*)d_ws + x_bytes;
        float*       sx = (float*)((char*)d_ws + x_bytes + w_bytes);

        quant_x_kernel<<<M_TOTAL, 256, 0, stream>>>(x, xq, sx);
        cvt_w_kernel<<<2048, 256, 0, stream>>>(wq, wb, (int)(w_bytes / 16));
        dim3 grid(NBM * NBN);  // 5504
        gemm_kernel<<<grid, 256, 0, stream>>>((const unsigned char*)xq,
                                              (const unsigned char*)wb,
                                              sx, scale, bias, out);
    } else {
        dim3 grid((M_TOTAL / 64) * (N_TOTAL / 64));
        gemm_fallback<<<grid, 256, 0, stream>>>(x, wq, scale, bias, out);
    }
}

// Round 7
// 462.504 us; speedup vs baseline: 1.0202x; 1.0202x over previous
//
#include <hip/hip_runtime.h>
#include <hip/hip_bf16.h>
#include <stdint.h>

// QuantizedLinear: y = x @ (Wq * scale[:,None])^T + bias
// Round 7: i8 MFMA. Diagnosis r4-r6: LDS BANDWIDTH-bound (192KiB/CU/K-tile at
// ~73 B/cyc measured == ceiling; MfmaUtil 45 == 1306/2639). Fix: reduce LDS
// bytes per FLOP via bigger per-wave tiles. Config: 256x256 tile, BK=128,
// 8 waves (2Mx4N), per-wave 128x64, 1 block/CU, 128 KiB LDS dbuf.
// Per CU/K-tile: MFMA 2611cyc vs LDS (192r+64w)KiB ~3100cyc -> ceiling ~80%.
// Pipeline = round-6's verified frag-ahead skeleton (explicit counted waits):
//   pre-read (post barB): afX[8]<-bq.A(K0), bf0[4],bf1[4]<-bq.B(K0,K1)
//   P0: RD afY[8]<-bp.A(K1) | STAGE A(t+1)->bq.A | MFMA(afX,bf0)
//       lgkmcnt(0) [ALL bp reads resolved]  barrier A
//   P1: STAGE B(t+2)->bp.B [safe: barA postdates bp.B-read drain]
//       MFMA(afY,bf1) | vmcnt(4) [A(t+1),B(t+1) landed; B(t+2) in flight]
//       barrier B | pre-read tile t+1 from bq

#define M_TOTAL 8192
#define K_TOTAL 4096
#define N_TOTAL 11008
#define NT 32
#define NBM 32                      // 8192/256
#define NBN 43                      // 11008/256

typedef __attribute__((ext_vector_type(4))) int int4v;

// ---------------- x quantization: per-row absmax -> int8 (verbatim r4) ----------------

__global__ __launch_bounds__(256) void quant_x_kernel(const float* __restrict__ x,
                                                      signed char* __restrict__ xq,
                                                      float* __restrict__ sx) {
    const int row = blockIdx.x;
    const int tid = threadIdx.x;
    const float* xr = x + (size_t)row * K_TOTAL + tid * 16;

    float4 v0 = reinterpret_cast<const float4*>(xr)[0];
    float4 v1 = reinterpret_cast<const float4*>(xr)[1];
    float4 v2 = reinterpret_cast<const float4*>(xr)[2];
    float4 v3 = reinterpret_cast<const float4*>(xr)[3];

    float m = 0.f;
    m = fmaxf(m, fmaxf(fmaxf(fabsf(v0.x), fabsf(v0.y)), fmaxf(fabsf(v0.z), fabsf(v0.w))));
    m = fmaxf(m, fmaxf(fmaxf(fabsf(v1.x), fabsf(v1.y)), fmaxf(fabsf(v1.z), fabsf(v1.w))));
    m = fmaxf(m, fmaxf(fmaxf(fabsf(v2.x), fabsf(v2.y)), fmaxf(fabsf(v2.z), fabsf(v2.w))));
    m = fmaxf(m, fmaxf(fmaxf(fabsf(v3.x), fabsf(v3.y)), fmaxf(fabsf(v3.z), fabsf(v3.w))));

    for (int d = 1; d < 64; d <<= 1) m = fmaxf(m, __shfl_xor(m, d));
    __shared__ float wm_[4];
    if ((tid & 63) == 0) wm_[tid >> 6] = m;
    __syncthreads();
    m = fmaxf(fmaxf(wm_[0], wm_[1]), fmaxf(wm_[2], wm_[3]));

    const float inv = (m > 0.f) ? (127.f / m) : 0.f;
    if (tid == 0) sx[row] = (m > 0.f) ? (m / 127.f) : 0.f;

    float tmp[16] = {v0.x,v0.y,v0.z,v0.w, v1.x,v1.y,v1.z,v1.w,
                     v2.x,v2.y,v2.z,v2.w, v3.x,v3.y,v3.z,v3.w};
    int q[16];
#pragma unroll
    for (int i = 0; i < 16; ++i) {
        int t = __float2int_rn(tmp[i] * inv);
        q[i] = t > 127 ? 127 : (t < -127 ? -127 : t);
    }
    int4v o;
#pragma unroll
    for (int w = 0; w < 4; ++w)
        o[w] = (q[w*4] & 255) | ((q[w*4+1] & 255) << 8) |
               ((q[w*4+2] & 255) << 16) | ((q[w*4+3] & 255) << 24);
    *reinterpret_cast<int4v*>(xq + (size_t)row * K_TOTAL + tid * 16) = o;
}

// ---------------- W unpack (verbatim r4) ----------------

__global__ __launch_bounds__(256) void cvt_w_kernel(const int* __restrict__ in,
                                                    signed char* __restrict__ out, int nitems) {
    bool is8 = false;
    for (int i = 0; i < 256; ++i) {
        int v = in[i];
        if (v < -127 || v > 127) { is8 = true; break; }
    }
    int stride = gridDim.x * blockDim.x;
    if (!is8) {
        for (int i = blockIdx.x * blockDim.x + threadIdx.x; i < nitems; i += stride) {
            const int* p = in + (size_t)i * 16;
            int4v o;
#pragma unroll
            for (int w = 0; w < 4; ++w)
                o[w] = (p[w*4] & 255) | ((p[w*4+1] & 255) << 8) |
                       ((p[w*4+2] & 255) << 16) | ((p[w*4+3] & 255) << 24);
            *reinterpret_cast<int4v*>(out + (size_t)i * 16) = o;
        }
    } else {
        const int4v* in16 = reinterpret_cast<const int4v*>(in);
        for (int i = blockIdx.x * blockDim.x + threadIdx.x; i < nitems; i += stride)
            *reinterpret_cast<int4v*>(out + (size_t)i * 16) = in16[i];
    }
}

// ---------------- 256x256 i8 GEMM, frag-ahead pipeline, 8 waves ----------------

#define GLOAD16(g, l) __builtin_amdgcn_global_load_lds( \
    (const __attribute__((address_space(1))) void*)(g), \
    (__attribute__((address_space(3))) void*)(l), 16, 0, 0)

// LDS (bytes): buf p*65536 + {A: [0,32K) | B: [32K,64K)}; tile t in buf[t&1].
// Tile = 256 rows x 128 B per operand. chunk = 8 rows = 1 KiB; 32 chunks/op;
// wave wv stages chunks wv*4..wv*4+3 per operand.
// Swizzle: 16B granule g stored at g ^ (row&7); inverse applied on global src.

#define RD_A8(dst, base, KX)                                                    \
    _Pragma("unroll")                                                           \
    for (int i_ = 0; i_ < 8; ++i_)                                              \
        dst[i_] = *(const int4v*)((base) + (wm * 128 + i_ * 16 + fr) * 128 + (KX));
#define RD_B4(dst, base, KX)                                                    \
    _Pragma("unroll")                                                           \
    for (int n_ = 0; n_ < 4; ++n_)                                              \
        dst[n_] = *(const int4v*)((base) + 32768 + (wn * 64 + n_ * 16 + fr) * 128 + (KX));
#define MFMA32(fa, fb)                                                          \
    __builtin_amdgcn_s_setprio(1);                                              \
    _Pragma("unroll")                                                           \
    for (int i_ = 0; i_ < 8; ++i_) {                                            \
        _Pragma("unroll")                                                       \
        for (int n_ = 0; n_ < 4; ++n_)                                          \
            acc[i_][n_] = __builtin_amdgcn_mfma_i32_16x16x64_i8(                \
                fa[i_], fb[n_], acc[i_][n_], 0, 0, 0);                          \
    }                                                                           \
    __builtin_amdgcn_s_setprio(0);
#define STAGE_A(asrc, buf)                                                      \
    _Pragma("unroll")                                                           \
    for (int i_ = 0; i_ < 4; ++i_)                                              \
        GLOAD16((asrc) + soff[i_], (buf) + (c0 + i_) * 1024);
#define STAGE_B(bsrc, buf)                                                      \
    _Pragma("unroll")                                                           \
    for (int i_ = 0; i_ < 4; ++i_)                                              \
        GLOAD16((bsrc) + soff[i_], (buf) + 32768 + (c0 + i_) * 1024);

__global__ __launch_bounds__(512, 2) void gemm_kernel(const unsigned char* __restrict__ A,
                                                      const unsigned char* __restrict__ B,
                                                      const float* __restrict__ sx,
                                                      const float* __restrict__ scale,
                                                      const float* __restrict__ bias,
                                                      float* __restrict__ C) {
    __shared__ unsigned char sh[131072];  // 128 KiB -> 1 block/CU

    const int tid  = threadIdx.x;
    const int wv   = tid >> 6;      // 0..7
    const int lane = tid & 63;
    const int wm   = wv >> 2;       // 0..1 (M half)
    const int wn   = wv & 3;        // 0..3 (N quarter)

    // XCD swizzle: 1376 = 8 xcd * 172; per-xcd 4 bm x 43 bn, bm-inner order
    // (4 A-panels = 4 MiB resident in XCD L2; B-panels stream).
    const int xcd = blockIdx.x & 7;
    const int l   = blockIdx.x >> 3;   // 0..171
    const int bm  = xcd * 4 + (l & 3);
    const int bn  = l >> 2;

    // fragment-read geometry (byte offsets)
    const int fr  = lane & 15;
    const int fq  = lane >> 4;
    const int swz = fr & 7;
    const int kx0 = (fq ^ swz) * 16;
    const int kx1 = ((4 + fq) ^ swz) * 16;

    // staging source offsets (inverse-swizzled granule)
    const int c0 = wv * 4;
    const int rl = lane >> 3;
    const int sg = (lane & 7) ^ rl;
    int soff[4];
#pragma unroll
    for (int i = 0; i < 4; ++i)
        soff[i] = ((c0 + i) * 8 + rl) * K_TOTAL + sg * 16;

    const unsigned char* aS = A + (size_t)bm * 256 * K_TOTAL;
    const unsigned char* bS = B + (size_t)bn * 256 * K_TOTAL;
    unsigned char* buf0 = sh;
    unsigned char* buf1 = sh + 65536;

    int4v acc[8][4] = {};
    int4v afX[8], afY[8], bf0v[4], bf1v[4];

    // ---- prologue: A(0),B(0)->buf0; B(1)->buf1.B; frag pre-reads of tile 0 ----
    STAGE_A(aS, buf0)
    STAGE_B(bS, buf0)
    STAGE_B(bS + 128, buf1)
    asm volatile("s_waitcnt vmcnt(4)" ::: "memory");   // tile0 landed; B(1) in flight
    __builtin_amdgcn_s_barrier();
    RD_A8(afX, buf0, kx0)
    RD_B4(bf0v, buf0, kx0)
    RD_B4(bf1v, buf0, kx1)

    // ---- main loop ----
#pragma unroll 1
    for (int t = 0; t < NT; ++t) {
        const int p = t & 1;
        unsigned char* bp = p ? buf1 : buf0;
        unsigned char* bq = p ? buf0 : buf1;

        // P0. WAR(bq.A): last bq.A reads (tile t-1's afY + pre-reads) resolved
        // at t-1's lgkmcnt(0) before its barrier A; two barriers ago. OK.
        RD_A8(afY, bp, kx1)
        if (t + 1 < NT) { STAGE_A(aS + (size_t)(t + 1) * 128, bq) }
        MFMA32(afX, bf0v)                                   // ops pre-read last tile
        asm volatile("s_waitcnt lgkmcnt(0)" ::: "memory");  // ALL bp reads resolved
        __builtin_amdgcn_s_barrier();                       // barrier A

        // P1. RAW-safe restage of bp.B: barA postdates every wave's lgkm(0).
        if (t + 2 < NT) { STAGE_B(bS + (size_t)(t + 2) * 128, bp) }
        MFMA32(afY, bf1v)
        if (t + 1 < NT) {
            if (t + 2 < NT) { asm volatile("s_waitcnt vmcnt(4)" ::: "memory"); }  // keep B(t+2) in flight
            else            { asm volatile("s_waitcnt vmcnt(0)" ::: "memory"); }
        }
        __builtin_amdgcn_s_barrier();                       // barrier B: bq fully staged
        if (t + 1 < NT) {
            RD_A8(afX, bq, kx0)                             // tile t+1 pre-reads;
            RD_B4(bf0v, bq, kx0)                            // complete under next P0 MFMA
            RD_B4(bf1v, bq, kx1)
        }
    }

    // ---- epilogue: y = acc * sx[row]*scale[col] + bias[col] ----
    const int crow0 = bm * 256 + wm * 128;
    const int ccol0 = bn * 256 + wn * 64;
    float scv[4], bsv[4];
#pragma unroll
    for (int n = 0; n < 4; ++n) {
        const int col = ccol0 + n * 16 + fr;
        scv[n] = scale[col];
        bsv[n] = bias[col];
    }
#pragma unroll
    for (int fm = 0; fm < 8; ++fm) {
#pragma unroll
        for (int j = 0; j < 4; ++j) {
            const int row = crow0 + fm * 16 + fq * 4 + j;
            const float sr = sx[row];
            float* cp = C + (size_t)row * N_TOTAL + ccol0 + fr;
#pragma unroll
            for (int n = 0; n < 4; ++n)
                cp[n * 16] = (float)acc[fm][n][j] * (sr * scv[n]) + bsv[n];
        }
    }
}

// ---------------- fallback (ws too small): tiled f32 vector GEMM ----------------

__global__ __launch_bounds__(256) void gemm_fallback(const float* __restrict__ x,
                                                     const int* __restrict__ w,
                                                     const float* __restrict__ scale,
                                                     const float* __restrict__ bias,
                                                     float* __restrict__ C) {
    bool is8 = false;
    for (int i = 0; i < 256; ++i) {
        int v = w[i];
        if (v < -127 || v > 127) { is8 = true; break; }
    }
    const signed char* w8 = (const signed char*)w;

    __shared__ float As[64][16];
    __shared__ float Bs[64][16];
    const int nbn = N_TOTAL / 64;
    const int bm = blockIdx.x / nbn;
    const int bn = blockIdx.x % nbn;
    const int tid = threadIdx.x;
    const int tx = tid & 15, ty = tid >> 4;

    float acc[4][4] = {};
    for (int kt = 0; kt < K_TOTAL; kt += 16) {
        for (int i = 0; i < 4; ++i) {
            int idx = tid + i * 256;
            int rr = idx >> 4, cc = idx & 15;
            As[rr][cc] = x[(size_t)(bm * 64 + rr) * K_TOTAL + kt + cc];
            size_t widx = (size_t)(bn * 64 + rr) * K_TOTAL + kt + cc;
            Bs[rr][cc] = is8 ? (float)w8[widx] : (float)w[widx];
        }
        __syncthreads();
        for (int kk = 0; kk < 16; ++kk) {
            float a[4], b[4];
            for (int i = 0; i < 4; ++i) a[i] = As[ty * 4 + i][kk];
            for (int j = 0; j < 4; ++j) b[j] = Bs[tx * 4 + j][kk];
            for (int i = 0; i < 4; ++i)
                for (int j = 0; j < 4; ++j) acc[i][j] += a[i] * b[j];
        }
        __syncthreads();
    }
    for (int j = 0; j < 4; ++j) {
        int col = bn * 64 + tx * 4 + j;
        float s = scale[col], bb = bias[col];
        for (int i = 0; i < 4; ++i) {
            int row = bm * 64 + ty * 4 + i;
            C[(size_t)row * N_TOTAL + col] = acc[i][j] * s + bb;
        }
    }
}

// ---------------- launch ----------------

extern "C" void kernel_launch(void* const* d_in, const int* in_sizes, int n_in,
                              void* d_out, int out_size, void* d_ws, size_t ws_size,
                              hipStream_t stream) {
    const float* x     = (const float*)d_in[0];
    const int*   wq    = (const int*)d_in[1];
    const float* scale = (const float*)d_in[2];
    const float* bias  = (const float*)d_in[3];
    float*       out   = (float*)d_out;

    const size_t x_bytes = (size_t)M_TOTAL * K_TOTAL;
    const size_t w_bytes = (size_t)N_TOTAL * K_TOTAL;
    const size_t need = x_bytes + w_bytes + M_TOTAL * sizeof(float);

    if (ws_size >= need) {
        signed char* xq = (signed char*)d_ws;
        signed char* wb = (signed char*)d_ws + x_bytes;
        float*       sx = (float*)((char*)d_ws + x_bytes + w_bytes);

        quant_x_kernel<<<M_TOTAL, 256, 0, stream>>>(x, xq, sx);
        cvt_w_kernel<<<2048, 256, 0, stream>>>(wq, wb, (int)(w_bytes / 16));
        dim3 grid(NBM * NBN);  // 32*43 = 1376
        gemm_kernel<<<grid, 512, 0, stream>>>((const unsigned char*)xq,
                                              (const unsigned char*)wb,
                                              sx, scale, bias, out);
    } else {
        dim3 grid((M_TOTAL / 64) * (N_TOTAL / 64));
        gemm_fallback<<<grid, 256, 0, stream>>>(x, wq, scale, bias, out);
    }
}